// Round 5
// baseline (485.578 us; speedup 1.0000x reference)
//
#include <hip/hip_runtime.h>

#define SEQn   512
#define BATCHn 4096
#define INn    9
#define HIDn   64
#define OUTn   10

typedef __attribute__((ext_vector_type(4))) float f32x4;
typedef _Float16 half2_t __attribute__((ext_vector_type(2)));
typedef unsigned short u16;

#if __has_builtin(__builtin_amdgcn_fdot2)
#define DOT2(a, b, c) __builtin_amdgcn_fdot2((a), (b), (c), false)
#else
__device__ __forceinline__ float DOT2(half2_t a, half2_t b, float c){
    return __builtin_fmaf((float)a.x, (float)b.x,
           __builtin_fmaf((float)a.y, (float)b.y, c));
}
#endif

__device__ __forceinline__ float fast_tanh(float x){
    float e = __builtin_amdgcn_exp2f(x * 2.8853900817779268f);  // e^(2x)
    float r = __builtin_amdgcn_rcpf(e + 1.0f);
    return __builtin_fmaf(-2.0f, r, 1.0f);
}

// lane-owned weight row: 64 f32 -> 32 half2 regs
__device__ __forceinline__ void load_wrow_f16(const float* __restrict__ W, int row,
                                              half2_t* wr){
#pragma unroll
    for (int c = 0; c < 16; ++c){
        f32x4 v = *(const f32x4*)&W[row*64 + c*4];
        wr[2*c]   = half2_t{(_Float16)v.x, (_Float16)v.y};
        wr[2*c+1] = half2_t{(_Float16)v.z, (_Float16)v.w};
    }
}

// 64-dot: v = 8 x uint4 (64 f16 broadcast vector), wr = 32 half2 regs
__device__ __forceinline__ float dot64v(const uint4* v, const half2_t* wr, float acc){
    float a0 = acc, a1 = 0.f, a2 = 0.f, a3 = 0.f;
#pragma unroll
    for (int jb = 0; jb < 8; ++jb){
        a0 = DOT2(__builtin_bit_cast(half2_t, v[jb].x), wr[jb*4+0], a0);
        a1 = DOT2(__builtin_bit_cast(half2_t, v[jb].y), wr[jb*4+1], a1);
        a2 = DOT2(__builtin_bit_cast(half2_t, v[jb].z), wr[jb*4+2], a2);
        a3 = DOT2(__builtin_bit_cast(half2_t, v[jb].w), wr[jb*4+3], a3);
    }
    return (a0 + a1) + (a2 + a3);
}

// Single-wave recurrence, zero barriers in the 513-step loop.
// Wave 0, iteration i (i = 1..511 main, 0 and 512[/513] peeled):
//   reads  h1[i-1] (2-slot LDS ping-pong, 8x ds_read_b128 broadcast)
//          h2[i-2] (same), x-row i from LDS
//   mv1: h1[i]   = tanh(x[i]·Wih0^T + b1 + Whh0·h1[i-1])   -> write slot (early)
//   mv2: u2[i-1] = b2 + Wih1·h1[i-1]                        (register, same iter)
//   mv3: h2[i-1] = tanh(u2[i-1] + Whh1·h2[i-2])             -> write slot
//   h2 history -> d_ws (u16, fire-and-forget)  [or inline FC if DOFC]
// The h1 RAW round trip hides under mv2/mv3; h2's hides under next iter's mv1.
template<bool DOFC>
__global__ __launch_bounds__(256, 1)
void rnn_lastrow(const float* __restrict__ x,
                 const float* __restrict__ Wih0, const float* __restrict__ Whh0,
                 const float* __restrict__ bih0, const float* __restrict__ bhh0,
                 const float* __restrict__ Wih1, const float* __restrict__ Whh1,
                 const float* __restrict__ bih1, const float* __restrict__ bhh1,
                 const float* __restrict__ Wfc,  const float* __restrict__ bfc,
                 float* __restrict__ out, u16* __restrict__ wsp)
{
    __shared__ __align__(16) float    xl[SEQn*12];     // x[:,4095,:], stride 12
    __shared__ __align__(16) _Float16 h1s[2][HIDn];
    __shared__ __align__(16) _Float16 h2s[2][HIDn];

    const int tid  = threadIdx.x;
    const int w    = tid >> 6;
    const int lane = tid & 63;

    // ---- phase 0: stage x[:, 4095, :] ----
    for (int idx = tid; idx < SEQn*INn; idx += 256){
        int s = idx / INn, ii = idx - s*INn;
        xl[s*12 + ii] = x[((long)s*BATCHn + (BATCHn-1))*INn + ii];
    }
    if (tid < 64){
        h1s[0][tid] = (_Float16)0.f; h1s[1][tid] = (_Float16)0.f;
        h2s[0][tid] = (_Float16)0.f; h2s[1][tid] = (_Float16)0.f;
    }

    // ---- wave-0 weights -> registers ----
    half2_t wr0[32], wr1[32], wr2[32], wfcl[32];
    float wx9[INn];
    float b1 = 0.f, b2 = 0.f, bo = 0.f;
    if (w == 0){
        load_wrow_f16(Whh0, lane, wr0);
        load_wrow_f16(Wih1, lane, wr1);
        load_wrow_f16(Whh1, lane, wr2);
#pragma unroll
        for (int j = 0; j < INn; ++j) wx9[j] = Wih0[lane*INn + j];
        b1 = bih0[lane] + bhh0[lane];
        b2 = bih1[lane] + bhh1[lane];
        if (DOFC && lane < OUTn){
            load_wrow_f16(Wfc, lane, wfcl);
            bo = bfc[lane];
        }
    }
    __syncthreads();

    if (w == 0){
        // ---- i = 0 peeled: h1[0] = tanh(x[0]·Wih0^T + b1) ----
        {
            float a0 = b1, a1 = 0.f, a2 = 0.f;
            const float* xr = &xl[0];
            a0 = __builtin_fmaf(xr[0], wx9[0], a0);
            a1 = __builtin_fmaf(xr[1], wx9[1], a1);
            a2 = __builtin_fmaf(xr[2], wx9[2], a2);
            a0 = __builtin_fmaf(xr[3], wx9[3], a0);
            a1 = __builtin_fmaf(xr[4], wx9[4], a1);
            a2 = __builtin_fmaf(xr[5], wx9[5], a2);
            a0 = __builtin_fmaf(xr[6], wx9[6], a0);
            a1 = __builtin_fmaf(xr[7], wx9[7], a1);
            a2 = __builtin_fmaf(xr[8], wx9[8], a2);
            h1s[0][lane] = (_Float16)fast_tanh((a0 + a1) + a2);
        }

        // ---- main loop: i = 1 .. 511, no barriers ----
        for (int i = 1; i < SEQn; ++i){
            const int par = i & 1;
            // broadcast reads (wave-uniform b128)
            const uint4* p1 = (const uint4*)h1s[par^1];   // h1[i-1]
            const uint4* p2 = (const uint4*)h2s[par];     // h2[i-2]
            uint4 v1[8], v2[8];
#pragma unroll
            for (int jb = 0; jb < 8; ++jb) v1[jb] = p1[jb];
#pragma unroll
            for (int jb = 0; jb < 8; ++jb) v2[jb] = p2[jb];

            // x-term (fp32 exact)
            const float* xr = &xl[i*12];
            f32x4 xa = *(const f32x4*)xr;
            f32x4 xb = *(const f32x4*)(xr + 4);
            float x8 = xr[8];
            float t0 = b1, t1 = 0.f, t2 = 0.f;
            t0 = __builtin_fmaf(xa.x, wx9[0], t0);
            t1 = __builtin_fmaf(xa.y, wx9[1], t1);
            t2 = __builtin_fmaf(xa.z, wx9[2], t2);
            t0 = __builtin_fmaf(xa.w, wx9[3], t0);
            t1 = __builtin_fmaf(xb.x, wx9[4], t1);
            t2 = __builtin_fmaf(xb.y, wx9[5], t2);
            t0 = __builtin_fmaf(xb.z, wx9[6], t0);
            t1 = __builtin_fmaf(xb.w, wx9[7], t1);
            t2 = __builtin_fmaf(x8,   wx9[8], t2);

            // mv1 -> h1[i], write slot EARLY so next iter's read latency hides
            float h1new = fast_tanh(dot64v(v1, wr0, (t0 + t1) + t2));
            h1s[par][lane] = (_Float16)h1new;

            // mv2: u2[i-1]   (same broadcast regs, no extra reads)
            float u2v = dot64v(v1, wr1, b2);
            // mv3 -> h2[i-1]
            _Float16 h2h = (_Float16)fast_tanh(dot64v(v2, wr2, u2v));
            h2s[par^1][lane] = h2h;
            if (!DOFC){
                wsp[(i-1)*HIDn + lane] = __builtin_bit_cast(u16, h2h);
            } else if (lane < OUTn && i >= 2){
                out[(i-2)*OUTn + lane] = dot64v(v2, wfcl, bo);  // uses h2[i-2]
            }
        }

        // ---- i = 512 peeled: mv2+mv3 only -> h2[511] ----
        {
            const uint4* p1 = (const uint4*)h1s[1];       // h1[511]
            const uint4* p2 = (const uint4*)h2s[0];       // h2[510]
            uint4 v1[8], v2[8];
#pragma unroll
            for (int jb = 0; jb < 8; ++jb) v1[jb] = p1[jb];
#pragma unroll
            for (int jb = 0; jb < 8; ++jb) v2[jb] = p2[jb];
            float u2v = dot64v(v1, wr1, b2);
            _Float16 h2h = (_Float16)fast_tanh(dot64v(v2, wr2, u2v));
            h2s[1][lane] = h2h;
            if (!DOFC){
                wsp[(SEQn-1)*HIDn + lane] = __builtin_bit_cast(u16, h2h);
            } else if (lane < OUTn){
                out[(SEQn-2)*OUTn + lane] = dot64v(v2, wfcl, bo);   // t = 510
            }
        }
        if (DOFC){
            // ---- i = 513: FC for t = 511 ----
            const uint4* p2 = (const uint4*)h2s[1];
            uint4 v2[8];
#pragma unroll
            for (int jb = 0; jb < 8; ++jb) v2[jb] = p2[jb];
            if (lane < OUTn) out[(SEQn-1)*OUTn + lane] = dot64v(v2, wfcl, bo);
        }
    }
    __syncthreads();

    // ---- phase 2 (ws path): FC over all t, 160 threads ----
    if (!DOFC && tid < 16*OUTn){
        const int o  = tid % OUTn;
        const int tb = tid / OUTn;          // 0..15, owns t = tb*32 .. +31
        half2_t wf[32];
        load_wrow_f16(Wfc, o, wf);
        const float bov = bfc[o];
        for (int j = 0; j < 32; ++j){
            const int t = tb*32 + j;
            const uint4* hp = (const uint4*)(wsp + t*HIDn);
            uint4 hv[8];
#pragma unroll
            for (int jb = 0; jb < 8; ++jb) hv[jb] = hp[jb];
            out[t*OUTn + o] = dot64v(hv, wf, bov);
        }
    }
}

extern "C" void kernel_launch(void* const* d_in, const int* in_sizes, int n_in,
                              void* d_out, int out_size, void* d_ws, size_t ws_size,
                              hipStream_t stream){
    const bool ws_ok = ws_size >= (size_t)(SEQn * HIDn * sizeof(u16));
    if (ws_ok){
        rnn_lastrow<false><<<dim3(1), dim3(256), 0, stream>>>(
            (const float*)d_in[0],
            (const float*)d_in[1], (const float*)d_in[2],
            (const float*)d_in[3], (const float*)d_in[4],
            (const float*)d_in[5], (const float*)d_in[6],
            (const float*)d_in[7], (const float*)d_in[8],
            (const float*)d_in[9], (const float*)d_in[10],
            (float*)d_out, (u16*)d_ws);
    } else {
        rnn_lastrow<true><<<dim3(1), dim3(256), 0, stream>>>(
            (const float*)d_in[0],
            (const float*)d_in[1], (const float*)d_in[2],
            (const float*)d_in[3], (const float*)d_in[4],
            (const float*)d_in[5], (const float*)d_in[6],
            (const float*)d_in[7], (const float*)d_in[8],
            (const float*)d_in[9], (const float*)d_in[10],
            (float*)d_out, (u16*)d_ws);
    }
}

// Round 6
// 358.322 us; speedup vs baseline: 1.3551x; 1.3551x over previous
//
#include <hip/hip_runtime.h>

#define SEQn   512
#define BATCHn 4096
#define INn    9
#define HIDn   64
#define OUTn   10

typedef __attribute__((ext_vector_type(4))) float f32x4;
typedef _Float16 half2_t __attribute__((ext_vector_type(2)));
typedef _Float16 half8   __attribute__((ext_vector_type(8)));
typedef unsigned short u16;
typedef unsigned int   u32;

#if __has_builtin(__builtin_amdgcn_fdot2)
#define DOT2(a,b,c) __builtin_amdgcn_fdot2((a),(b),(c),false)
#else
__device__ __forceinline__ float DOT2(half2_t a, half2_t b, float c){
    return __builtin_fmaf((float)a.x,(float)b.x, __builtin_fmaf((float)a.y,(float)b.y,c));
}
#endif

#define MFMA16(A,B,C) __builtin_amdgcn_mfma_f32_16x16x32_f16((A),(B),(C),0,0,0)

__device__ __forceinline__ float fast_tanh(float x){
    float e = __builtin_amdgcn_exp2f(x * 2.8853900817779268f);   // e^(2x)
    float r = __builtin_amdgcn_rcpf(e + 1.0f);
    return __builtin_fmaf(-2.0f, r, 1.0f);
}

__device__ __forceinline__ u32 pkf16(float a, float b){
    u16 ha = __builtin_bit_cast(u16, (_Float16)a);
    u16 hb = __builtin_bit_cast(u16, (_Float16)b);
    return (u32)ha | ((u32)hb << 16);
}

// B-frag for mfma_f32_16x16x32_f16: lane holds B[k][n]=W[n][k], n=lane&15 (+16*tile),
// k = 32*chunk + 8*(lane>>4) + j.  Rows n>=valid range -> zeros.
__device__ __forceinline__ half8 load_bfrag(const float* __restrict__ W, int n, int k0,
                                            bool valid){
    uint4 t{0u,0u,0u,0u};
    if (valid){
        const float* p = W + n*HIDn + k0;
        f32x4 v0 = *(const f32x4*)p;
        f32x4 v1 = *(const f32x4*)(p+4);
        t = uint4{pkf16(v0.x,v0.y), pkf16(v0.z,v0.w), pkf16(v1.x,v1.y), pkf16(v1.z,v1.w)};
    }
    return __builtin_bit_cast(half8, t);
}

__device__ __forceinline__ float dppx1(float v){     // value from lane^1
#if __has_builtin(__builtin_amdgcn_mov_dpp)
    return __builtin_bit_cast(float,
        __builtin_amdgcn_mov_dpp(__builtin_bit_cast(int, v), 0xB1, 0xF, 0xF, false));
#else
    return __shfl_xor(v, 1, 64);
#endif
}

// pair (h[2m], h[2m+1]) valid on every lane
__device__ __forceinline__ u32 mkpair(float self, float nb, bool odd){
    u16 a = __builtin_bit_cast(u16, (_Float16)self);
    u16 b = __builtin_bit_cast(u16, (_Float16)nb);
    u32 lo = odd ? (u32)b : (u32)a;
    u32 hi = odd ? (u32)a : (u32)b;
    return lo | (hi << 16);
}

// replicated-A frag: slot j' (k = base + j') for j'=0..7; fetch 4 packed pairs
// from lanes base+{0,2,4,6}. addr = 4*base (bpermute addr is lane*4).
__device__ __forceinline__ half8 aprep(u32 hpk, int addr){
    u32 p0 = (u32)__builtin_amdgcn_ds_bpermute(addr,      (int)hpk);
    u32 p1 = (u32)__builtin_amdgcn_ds_bpermute(addr + 8,  (int)hpk);
    u32 p2 = (u32)__builtin_amdgcn_ds_bpermute(addr + 16, (int)hpk);
    u32 p3 = (u32)__builtin_amdgcn_ds_bpermute(addr + 24, (int)hpk);
    uint4 t{p0,p1,p2,p3};
    return __builtin_bit_cast(half8, t);
}

// 64x64 matvec: 4 col-tiles x 2 K-chunks; lane l gets y[l] (tile l>>4, col l&15,
// rows replicated so acc[0] is the value).
#define MV64(Bv, A0, A1, q1c, q2c, outv) {                 \
    f32x4 zz{0.f,0.f,0.f,0.f};                             \
    f32x4 c0 = MFMA16(A0, Bv[0], zz); c0 = MFMA16(A1, Bv[1], c0); \
    f32x4 c1 = MFMA16(A0, Bv[2], zz); c1 = MFMA16(A1, Bv[3], c1); \
    f32x4 c2 = MFMA16(A0, Bv[4], zz); c2 = MFMA16(A1, Bv[5], c2); \
    f32x4 c3 = MFMA16(A0, Bv[6], zz); c3 = MFMA16(A1, Bv[7], c3); \
    float s01 = (q1c) ? c1[0] : c0[0];                     \
    float s23 = (q1c) ? c3[0] : c2[0];                     \
    outv = (q2c) ? s23 : s01;                              \
}

__device__ __forceinline__ void xread(const u16* xl, int row, uint4* a, u32* b){
    const u32* p = (const u32*)(xl + row*16);
    *a = *(const uint4*)p;     // halfs 0..7
    *b = p[4];                 // halfs 8,9 = (x8, 0)
}

__device__ __forceinline__ float xdot(uint4 xa, u32 xb, const half2_t* wx, float b1){
    float u = b1;
    u = DOT2(__builtin_bit_cast(half2_t, xa.x), wx[0], u);
    u = DOT2(__builtin_bit_cast(half2_t, xa.y), wx[1], u);
    u = DOT2(__builtin_bit_cast(half2_t, xa.z), wx[2], u);
    u = DOT2(__builtin_bit_cast(half2_t, xa.w), wx[3], u);
    u = DOT2(__builtin_bit_cast(half2_t, xb),   wx[4], u);
    return u;
}

// Only batch row 4095 reaches the output. Single wave does the whole recurrence:
// zero LDS round-trips for h (register scalar -> ds_bpermute -> replicated MFMA
// A-frag), weights as MFMA B-frags in VGPRs, x-term via f16 dot2 from LDS
// (prefetched 2 rows ahead), FC fused (2 MFMA on the already-prepped h2 frag).
// No barriers after staging; waves 1-3 exit.
extern "C" __global__ __launch_bounds__(256, 1)
void rnn_lastrow(const float* __restrict__ x,
                 const float* __restrict__ Wih0, const float* __restrict__ Whh0,
                 const float* __restrict__ bih0, const float* __restrict__ bhh0,
                 const float* __restrict__ Wih1, const float* __restrict__ Whh1,
                 const float* __restrict__ bih1, const float* __restrict__ bhh1,
                 const float* __restrict__ Wfc,  const float* __restrict__ bfc,
                 float* __restrict__ out)
{
    __shared__ __align__(16) u16 xl16[SEQn*16];   // x[:,4095,:] f16, rows padded to 16

    const int tid  = threadIdx.x;
    const int w    = tid >> 6;
    const int lane = tid & 63;

    half8 B1[8], B2[8], B3[8], Bf0, Bf1;
    half2_t wx[5];
    float b1 = 0.f, b2 = 0.f, bo = 0.f;

    if (w != 0){
        // waves 1-3: stage x[:, 4095, :] as f16 (single pass, pad slots -> 0)
        for (int idx = tid - 64; idx < SEQn*16; idx += 192){
            int t = idx >> 4, j = idx & 15;
            float v = (j < INn) ? x[((long)t*BATCHn + (BATCHn-1))*INn + j] : 0.f;
            xl16[idx] = __builtin_bit_cast(u16, (_Float16)v);
        }
    } else {
        // wave 0: weights -> register B-frags (overlaps staging)
        const int nc = lane & 15, q = lane >> 4;
#pragma unroll
        for (int c = 0; c < 4; ++c){
#pragma unroll
            for (int s = 0; s < 2; ++s){
                const int n = 16*c + nc, k0 = 32*s + 8*q;
                B1[c*2+s] = load_bfrag(Whh0, n, k0, true);
                B2[c*2+s] = load_bfrag(Wih1, n, k0, true);
                B3[c*2+s] = load_bfrag(Whh1, n, k0, true);
            }
        }
        Bf0 = load_bfrag(Wfc, nc, 8*q,      nc < OUTn);
        Bf1 = load_bfrag(Wfc, nc, 32 + 8*q, nc < OUTn);
        const float* wr = Wih0 + lane*INn;
#pragma unroll
        for (int p = 0; p < 4; ++p)
            wx[p] = half2_t{(_Float16)wr[2*p], (_Float16)wr[2*p+1]};
        wx[4] = half2_t{(_Float16)wr[8], (_Float16)0.f};
        b1 = bih0[lane] + bhh0[lane];
        b2 = bih1[lane] + bhh1[lane];
        bo = (lane < OUTn) ? bfc[lane] : 0.f;
    }
    __syncthreads();
    if (w != 0) return;

    const bool lodd = lane & 1;
    const bool q1   = (lane >> 4) & 1;
    const bool q2   = lane >= 32;
    const int a0addr = 4*(8*(lane >> 4));          // A chunk 0 source lanes
    const int a1addr = 4*(32 + 8*(lane >> 4));     // A chunk 1

    uint4 xa0, xa1; u32 xb0, xb1;
    float h1v, h2v = 0.f;

    // peel i=0: h1[0] = tanh(x[0]·Wih0^T + b1)
    xread(xl16, 0, &xa0, &xb0);
    h1v = fast_tanh(xdot(xa0, xb0, wx, b1));
    xread(xl16, 1, &xa0, &xb0);
    xread(xl16, 2, &xa1, &xb1);

    for (int i = 1; i <= SEQn; ++i){
        // A-frags from register scalars (h1[i-1], h2[i-2])
        float n1 = dppx1(h1v); u32 hp1 = mkpair(h1v, n1, lodd);
        float n2 = dppx1(h2v); u32 hp2 = mkpair(h2v, n2, lodd);
        half8 A10 = aprep(hp1, a0addr), A11 = aprep(hp1, a1addr);
        half8 A20 = aprep(hp2, a0addr), A21 = aprep(hp2, a1addr);

        // x-term for this step; rotate prefetch (2 ahead, clamped)
        float u1 = xdot(xa0, xb0, wx, b1);
        xa0 = xa1; xb0 = xb1;
        int nr = (i + 2 > SEQn - 1) ? (SEQn - 1) : (i + 2);
        xread(xl16, nr, &xa1, &xb1);

        float y1; MV64(B1, A10, A11, q1, q2, y1);      // Whh0·h1[i-1]
        float h1n = fast_tanh(y1 + u1);
        float u2; MV64(B2, A10, A11, q1, q2, u2);      // Wih1·h1[i-1]
        float y3; MV64(B3, A20, A21, q1, q2, y3);      // Whh1·h2[i-2]
        float h2n = fast_tanh(y3 + u2 + b2);

        // fused FC on h2[i-2] (A2 frags already built): out row t = i-2
        if (i >= 2){
            f32x4 zz{0.f,0.f,0.f,0.f};
            f32x4 c = MFMA16(A20, Bf0, zz);
            c = MFMA16(A21, Bf1, c);
            if (lane < OUTn) out[(i-2)*OUTn + lane] = c[0] + bo;
        }
        h1v = h1n; h2v = h2n;
    }

    // epilogue: FC for t = 511 on h2[511]
    {
        float n2 = dppx1(h2v); u32 hp2 = mkpair(h2v, n2, lodd);
        half8 A20 = aprep(hp2, a0addr), A21 = aprep(hp2, a1addr);
        f32x4 zz{0.f,0.f,0.f,0.f};
        f32x4 c = MFMA16(A20, Bf0, zz);
        c = MFMA16(A21, Bf1, c);
        if (lane < OUTn) out[(SEQn-1)*OUTn + lane] = c[0] + bo;
    }
}

extern "C" void kernel_launch(void* const* d_in, const int* in_sizes, int n_in,
                              void* d_out, int out_size, void* d_ws, size_t ws_size,
                              hipStream_t stream){
    rnn_lastrow<<<dim3(1), dim3(256), 0, stream>>>(
        (const float*)d_in[0],
        (const float*)d_in[1], (const float*)d_in[2],
        (const float*)d_in[3], (const float*)d_in[4],
        (const float*)d_in[5], (const float*)d_in[6],
        (const float*)d_in[7], (const float*)d_in[8],
        (const float*)d_in[9], (const float*)d_in[10],
        (float*)d_out);
}

// Round 7
// 270.431 us; speedup vs baseline: 1.7956x; 1.3250x over previous
//
#include <hip/hip_runtime.h>

#define SEQn   512
#define BATCHn 4096
#define INn    9
#define HIDn   64
#define OUTn   10

typedef __attribute__((ext_vector_type(4))) float f32x4;
typedef _Float16 half2_t __attribute__((ext_vector_type(2)));
typedef unsigned short u16;
typedef unsigned int   u32;

#if __has_builtin(__builtin_amdgcn_fdot2)
#define DOT2(a,b,c) __builtin_amdgcn_fdot2((a),(b),(c),false)
#else
__device__ __forceinline__ float DOT2(half2_t a, half2_t b, float c){
    return __builtin_fmaf((float)a.x,(float)b.x, __builtin_fmaf((float)a.y,(float)b.y,c));
}
#endif
#define H2(u) __builtin_bit_cast(half2_t, (u))

__device__ __forceinline__ float fast_tanh(float x){
    float e = __builtin_amdgcn_exp2f(x * 2.8853900817779268f);   // e^(2x)
    float r = __builtin_amdgcn_rcpf(e + 1.0f);
    return __builtin_fmaf(-2.0f, r, 1.0f);
}
__device__ __forceinline__ u16 f2h(float v){
    return __builtin_bit_cast(u16, (_Float16)v);
}

// lane-owned weight row: 64 f32 -> 32 half2 regs
__device__ __forceinline__ void load_w16(const float* __restrict__ W, int row, half2_t* wr){
#pragma unroll
    for (int c = 0; c < 16; ++c){
        f32x4 v = *(const f32x4*)&W[row*HIDn + c*4];
        wr[2*c]   = half2_t{(_Float16)v.x, (_Float16)v.y};
        wr[2*c+1] = half2_t{(_Float16)v.z, (_Float16)v.w};
    }
}

// 64-dot: v = 8 x uint4 (64 f16), wr = 32 half2 regs, fp32 accumulate
__device__ __forceinline__ float dot64r(const uint4* v, const half2_t* wr, float acc){
    float a0 = acc, a1 = 0.f, a2 = 0.f, a3 = 0.f;
#pragma unroll
    for (int jb = 0; jb < 8; ++jb){
        a0 = DOT2(H2(v[jb].x), wr[jb*4+0], a0);
        a1 = DOT2(H2(v[jb].y), wr[jb*4+1], a1);
        a2 = DOT2(H2(v[jb].z), wr[jb*4+2], a2);
        a3 = DOT2(H2(v[jb].w), wr[jb*4+3], a3);
    }
    return (a0 + a1) + (a2 + a3);
}

// Only batch row 4095 reaches the output. Two decoupled recurrence chains:
//   wave0: h1[p] = tanh(x[p]·Wih0^T + b1 + Whh0·h1[p-1]); in its LDS-read
//          latency shadow computes u2[p-2] = Wih1·h1[p-2] + b2 (from the
//          previous iteration's broadcast regs) -> 64-deep LDS ring.
//   wave1: h2[c] = tanh(u2[c] + Whh1·h2[c-1]); shadow computes FC[c-2].
// No barriers in the loop: watermark words polled once per 8 iterations.
// h broadcast = per-lane ds_write_b16 + 8x ds_read_b128 (same-wave, in-order LDS).
extern "C" __global__ __launch_bounds__(256, 1)
void rnn_lastrow(const float* __restrict__ x,
                 const float* __restrict__ Wih0, const float* __restrict__ Whh0,
                 const float* __restrict__ bih0, const float* __restrict__ bhh0,
                 const float* __restrict__ Wih1, const float* __restrict__ Whh1,
                 const float* __restrict__ bih1, const float* __restrict__ bhh1,
                 const float* __restrict__ Wfc,  const float* __restrict__ bfc,
                 float* __restrict__ out)
{
    __shared__ __align__(16) u16   xl16[SEQn*16];     // x[:,4095,:] f16, rows padded
    __shared__ __align__(16) float u2r[64*HIDn];      // u2 ring, 64 slots
    __shared__ __align__(16) u16   h1buf[HIDn];
    __shared__ __align__(16) u16   h2buf[HIDn];
    __shared__ u32 wm[2];                             // [0]=u2 count ready, [1]=consumer iter

    const int tid  = threadIdx.x;
    const int w    = tid >> 6;
    const int lane = tid & 63;
    volatile u32* vwm = wm;

    // ---- stage x[:, 4095, :] as f16 (all waves) ----
    for (int idx = tid; idx < SEQn*16; idx += 256){
        int t = idx >> 4, j = idx & 15;
        float v = (j < INn) ? x[((long)t*BATCHn + (BATCHn-1))*INn + j] : 0.f;
        xl16[idx] = f2h(v);
    }
    if (tid < 64){ h1buf[tid] = 0; h2buf[tid] = 0; }
    if (tid == 0){ wm[0] = 0u; wm[1] = 0u; }
    __syncthreads();
    if (w >= 2) return;

    if (w == 0){
        // ================= producer: h1 chain + u2 ring =================
        half2_t wr0[32], wr1[32], wx[5];
        load_w16(Whh0, lane, wr0);
        load_w16(Wih1, lane, wr1);
        const float* wxr = Wih0 + lane*INn;
#pragma unroll
        for (int p = 0; p < 4; ++p)
            wx[p] = half2_t{(_Float16)wxr[2*p], (_Float16)wxr[2*p+1]};
        wx[4] = half2_t{(_Float16)wxr[8], (_Float16)0.f};
        const float b1 = bih0[lane] + bhh0[lane];
        const float b2 = bih1[lane] + bhh1[lane];

        uint4 va[8], vb[8];

        auto w0step = [&](int p, uint4* CUR, const uint4* PRV){
            if ((p & 7) == 0){
                asm volatile("s_waitcnt lgkmcnt(0)" ::: "memory");
                vwm[0] = (p >= 2) ? (u32)(p - 2) : 0u;
                while (vwm[1] + 58u <= (u32)p) __builtin_amdgcn_s_sleep(2);
            }
#pragma unroll
            for (int j = 0; j < 8; ++j) CUR[j] = ((const uint4*)h1buf)[j];
            const u32* xr = (const u32*)(xl16 + p*16);
            uint4 xa = *(const uint4*)xr;
            u32  xb = xr[4];
            if (p >= 2){   // latency shadow: u2[p-2] from prev broadcast regs
                float u2v = dot64r(PRV, wr1, b2);
                u2r[((p-2)&63)*HIDn + lane] = u2v;
            }
            float u1 = b1;
            u1 = DOT2(H2(xa.x), wx[0], u1);
            u1 = DOT2(H2(xa.y), wx[1], u1);
            u1 = DOT2(H2(xa.z), wx[2], u1);
            u1 = DOT2(H2(xa.w), wx[3], u1);
            u1 = DOT2(H2(xb),   wx[4], u1);
            float y = dot64r(CUR, wr0, 0.f);
            h1buf[lane] = f2h(fast_tanh(y + u1));
        };

        for (int p = 0; p < SEQn; p += 2){
            w0step(p,     va, vb);
            w0step(p + 1, vb, va);
        }
        // epilogue: u2[510] from vb (=h1[510]); u2[511] from fresh read of h1[511]
        {
            float u2v = dot64r(vb, wr1, b2);
            u2r[(510 & 63)*HIDn + lane] = u2v;
            uint4 vf[8];
#pragma unroll
            for (int j = 0; j < 8; ++j) vf[j] = ((const uint4*)h1buf)[j];
            u2v = dot64r(vf, wr1, b2);
            u2r[(511 & 63)*HIDn + lane] = u2v;
            asm volatile("s_waitcnt lgkmcnt(0)" ::: "memory");
            vwm[0] = (u32)SEQn;
        }
    } else {
        // ================= consumer: h2 chain + FC =================
        half2_t wr2[32], wfc[32];
        load_w16(Whh1, lane, wr2);
        load_w16(Wfc, (lane < OUTn) ? lane : (OUTn-1), wfc);
        const float bo = (lane < OUTn) ? bfc[lane] : 0.f;

        uint4 va[8], vb[8];

        auto w1step = [&](int c, uint4* CUR, const uint4* PRV){
            if ((c & 7) == 0){
                vwm[1] = (u32)c;
                while (vwm[0] < (u32)(c + 8)) __builtin_amdgcn_s_sleep(2);
            }
#pragma unroll
            for (int j = 0; j < 8; ++j) CUR[j] = ((const uint4*)h2buf)[j];
            float u2v = *((volatile float*)&u2r[(c & 63)*HIDn + lane]);
            if (c >= 2 && lane < OUTn){   // latency shadow: FC for t = c-2
                float fc = dot64r(PRV, wfc, bo);
                out[(c-2)*OUTn + lane] = fc;
            }
            float y = dot64r(CUR, wr2, u2v);
            h2buf[lane] = f2h(fast_tanh(y));
        };

        for (int c = 0; c < SEQn; c += 2){
            w1step(c,     va, vb);
            w1step(c + 1, vb, va);
        }
        // epilogue: FC[510] from vb (=h2[510]); FC[511] from fresh read of h2[511]
        if (lane < OUTn){
            float fc = dot64r(vb, wfc, bo);
            out[510*OUTn + lane] = fc;
        }
        {
            uint4 vf[8];
#pragma unroll
            for (int j = 0; j < 8; ++j) vf[j] = ((const uint4*)h2buf)[j];
            if (lane < OUTn){
                float fc = dot64r(vf, wfc, bo);
                out[511*OUTn + lane] = fc;
            }
        }
    }
}

extern "C" void kernel_launch(void* const* d_in, const int* in_sizes, int n_in,
                              void* d_out, int out_size, void* d_ws, size_t ws_size,
                              hipStream_t stream){
    rnn_lastrow<<<dim3(1), dim3(256), 0, stream>>>(
        (const float*)d_in[0],
        (const float*)d_in[1], (const float*)d_in[2],
        (const float*)d_in[3], (const float*)d_in[4],
        (const float*)d_in[5], (const float*)d_in[6],
        (const float*)d_in[7], (const float*)d_in[8],
        (const float*)d_in[9], (const float*)d_in[10],
        (float*)d_out);
}